// Round 1
// baseline (184.665 us; speedup 1.0000x reference)
//
#include <hip/hip_runtime.h>

#define Bv 8
#define Cc 256
#define Nn 2304
#define EPS 1e-5f

typedef float f32x4 __attribute__((ext_vector_type(4)));
typedef __bf16 bf16x8 __attribute__((ext_vector_type(8)));

static __device__ __forceinline__ f32x4 mfma16(bf16x8 a, bf16x8 b, f32x4 c) {
    return __builtin_amdgcn_mfma_f32_16x16x32_bf16(a, b, c, 0, 0, 0);
}

// load 8 contiguous fp32 and convert to bf16x8
static __device__ __forceinline__ bf16x8 load_cvt8(const float* __restrict__ p) {
    float4 a = *(const float4*)p;
    float4 b = *(const float4*)(p + 4);
    bf16x8 r;
    r[0] = (__bf16)a.x; r[1] = (__bf16)a.y; r[2] = (__bf16)a.z; r[3] = (__bf16)a.w;
    r[4] = (__bf16)b.x; r[5] = (__bf16)b.y; r[6] = (__bf16)b.z; r[7] = (__bf16)b.w;
    return r;
}

// ---------------------------------------------------------------------------
// K2a: L = diag(inv) * (Wz @ Wv)   [256x256] bf16
//      Rt = Wq^T @ Wk              [256x256] bf16   (Rt[j,i] = sum_o Wq[o,j] Wk[o,i])
// Simple fp32 LDS-dot kernel; 512 blocks of 16x16 output tiles.
// ---------------------------------------------------------------------------
__global__ __launch_bounds__(256) void k_lr(
    const float* __restrict__ Wq, const float* __restrict__ Wk,
    const float* __restrict__ Wv, const float* __restrict__ Wz,
    const float* __restrict__ gamma, const float* __restrict__ var_,
    unsigned short* __restrict__ Lb_us, unsigned short* __restrict__ Rtb_us) {
    __shared__ float bufA[4096];
    __shared__ float bufB[4096];
    __bf16* Lb  = (__bf16*)Lb_us;
    __bf16* Rtb = (__bf16*)Rtb_us;
    int blk = blockIdx.x, tid = threadIdx.x;
    bool isL = (blk < 256);
    int t = isL ? blk : blk - 256;
    int tr = (t >> 4) * 16, tc = (t & 15) * 16;
    if (isL) {
        for (int idx = tid; idx < 4096; idx += 256) {
            int r = idx >> 8, m = idx & 255;
            bufA[idx] = Wz[(tr + r) * 256 + m];          // [16][256] rows of Wz
        }
        for (int idx = tid; idx < 4096; idx += 256) {
            int m = idx >> 4, j = idx & 15;
            bufB[idx] = Wv[m * 256 + tc + j];            // [256][16] cols of Wv
        }
    } else {
        for (int idx = tid; idx < 4096; idx += 256) {
            int o = idx >> 4, j = idx & 15;
            bufA[idx] = Wq[o * 256 + tr + j];            // [256][16] cols of Wq
            bufB[idx] = Wk[o * 256 + tc + j];            // [256][16] cols of Wk
        }
    }
    __syncthreads();
    int oo = tid >> 4, cc = tid & 15;
    float sum = 0.f;
    if (isL) {
#pragma unroll 8
        for (int m = 0; m < 256; ++m) sum += bufA[oo * 256 + m] * bufB[m * 16 + cc];
        int o = tr + oo;
        float inv = gamma[o] / sqrtf(var_[o] + EPS);
        Lb[o * 256 + tc + cc] = (__bf16)(inv * sum);
    } else {
#pragma unroll 8
        for (int o = 0; o < 256; ++o) sum += bufA[o * 16 + oo] * bufB[o * 16 + cc];
        Rtb[(tr + oo) * 256 + tc + cc] = (__bf16)sum;
    }
}

// ---------------------------------------------------------------------------
// T0: Qft[b][n][c] = (bf16) Qf[b][c][n]   (transpose so final GEMM is NT)
// ---------------------------------------------------------------------------
__global__ __launch_bounds__(256) void k_transpose(
    const float* __restrict__ Qf, unsigned short* __restrict__ Qft_us) {
    __shared__ float tile[64][65];
    __bf16* Qft = (__bf16*)Qft_us;
    int c0 = blockIdx.x * 64, n0 = blockIdx.y * 64, b = blockIdx.z;
    const float* src = Qf + (size_t)b * Cc * Nn;
    int tid = threadIdx.x;
    for (int idx = tid; idx < 4096; idx += 256) {
        int r = idx >> 6, cl = idx & 63;
        tile[r][cl] = src[(size_t)(c0 + r) * Nn + n0 + cl];
    }
    __syncthreads();
    __bf16* dst = Qft + ((size_t)b * Nn + n0) * 256 + c0;
    for (int idx = tid; idx < 4096; idx += 256) {
        int n = idx >> 6, c = idx & 63;
        dst[(size_t)n * 256 + c] = (__bf16)tile[c][n];
    }
}

// ---------------------------------------------------------------------------
// K1: S[b] += KVf[b] @ KVf[b]^T / N   (split-K atomic MFMA syrk)
// grid 256 = 8 b x 4 quad(128x128) x 8 kchunk(288); 4 waves, each 64x64.
// ---------------------------------------------------------------------------
__global__ __launch_bounds__(256) void k_syrk(
    const float* __restrict__ KVf, float* __restrict__ S) {
    __shared__ __bf16 As[128][40];   // pad 32->40 elems (80B pitch): conflict-free-ish
    __shared__ __bf16 Bs[128][40];
    int blk = blockIdx.x;
    int b = blk >> 5;
    int quad = (blk >> 3) & 3;
    int kc = blk & 7;
    int rq = quad >> 1, cq = quad & 1;
    int k0 = kc * 288;
    int tid = threadIdx.x;
    int l = tid & 63, w = tid >> 6;
    int wr = w >> 1, wc = w & 1;
    f32x4 zero = {0.f, 0.f, 0.f, 0.f};
    f32x4 acc[4][4];
#pragma unroll
    for (int i = 0; i < 4; ++i)
#pragma unroll
        for (int j = 0; j < 4; ++j) acc[i][j] = zero;

    const float* Abase = KVf + ((size_t)b * Cc + rq * 128) * Nn + k0;
    const float* Bbase = KVf + ((size_t)b * Cc + cq * 128) * Nn + k0;
    int r2 = tid >> 2, cg = (tid & 3) * 8;
    int lr = l & 15, kofs = (l >> 4) * 8;

    for (int ks = 0; ks < 9; ++ks) {
#pragma unroll
        for (int p = 0; p < 2; ++p) {
            int row = p * 64 + r2;
            *(bf16x8*)&As[row][cg] = load_cvt8(Abase + (size_t)row * Nn + ks * 32 + cg);
            *(bf16x8*)&Bs[row][cg] = load_cvt8(Bbase + (size_t)row * Nn + ks * 32 + cg);
        }
        __syncthreads();
        bf16x8 af[4], bb[4];
#pragma unroll
        for (int i = 0; i < 4; ++i) af[i] = *(const bf16x8*)&As[wr * 64 + i * 16 + lr][kofs];
#pragma unroll
        for (int j = 0; j < 4; ++j) bb[j] = *(const bf16x8*)&Bs[wc * 64 + j * 16 + lr][kofs];
#pragma unroll
        for (int i = 0; i < 4; ++i)
#pragma unroll
            for (int j = 0; j < 4; ++j)
                acc[i][j] = mfma16(af[i], bb[j], acc[i][j]);
        __syncthreads();
    }
    const float scale = 1.0f / (float)Nn;
    float* Sb = S + ((size_t)b << 16);
#pragma unroll
    for (int i = 0; i < 4; ++i) {
        int row0 = rq * 128 + wr * 64 + i * 16 + ((l >> 4) << 2);
#pragma unroll
        for (int j = 0; j < 4; ++j) {
            int col = cq * 128 + wc * 64 + j * 16 + lr;
#pragma unroll
            for (int r = 0; r < 4; ++r)
                atomicAdd(&Sb[(size_t)(row0 + r) * 256 + col], acc[i][j][r] * scale);
        }
    }
}

// ---------------------------------------------------------------------------
// K2b1: T[b] = L @ S[b]   (NT via S symmetry; no LDS, frags direct from L1/L2)
// grid 128 = 8 b x 16 tiles(64x64); 4 waves, each 16 rows x 64 cols.
// ---------------------------------------------------------------------------
__global__ __launch_bounds__(256) void k_LS(
    const unsigned short* __restrict__ Lb_us, const float* __restrict__ S,
    unsigned short* __restrict__ Tb_us) {
    const __bf16* Lb = (const __bf16*)Lb_us;
    __bf16* Tb = (__bf16*)Tb_us;
    int blk = blockIdx.x;
    int b = blk >> 4, t = blk & 15;
    int tr = (t >> 2) * 64, tc = (t & 3) * 64;
    int tid = threadIdx.x, l = tid & 63, w = tid >> 6;
    int lr = l & 15, kofs = (l >> 4) * 8;
    const float* Sb = S + ((size_t)b << 16);
    f32x4 zero = {0.f, 0.f, 0.f, 0.f};
    f32x4 acc[4] = {zero, zero, zero, zero};
    int arow = tr + w * 16 + lr;
    for (int kk = 0; kk < 256; kk += 32) {
        bf16x8 af = *(const bf16x8*)&Lb[arow * 256 + kk + kofs];
#pragma unroll
        for (int j = 0; j < 4; ++j) {
            int brow = tc + j * 16 + lr;
            bf16x8 bb = load_cvt8(&Sb[(size_t)brow * 256 + kk + kofs]);
            acc[j] = mfma16(af, bb, acc[j]);
        }
    }
    __bf16* Tbb = Tb + ((size_t)b << 16);
    int row0 = tr + w * 16 + ((l >> 4) << 2);
#pragma unroll
    for (int j = 0; j < 4; ++j) {
        int col = tc + j * 16 + lr;
#pragma unroll
        for (int r = 0; r < 4; ++r)
            Tbb[(size_t)(row0 + r) * 256 + col] = (__bf16)acc[j][r];
    }
}

// ---------------------------------------------------------------------------
// K2b2: P[b] = T[b] @ R  (Bt = Rt bf16)
// ---------------------------------------------------------------------------
__global__ __launch_bounds__(256) void k_TR(
    const unsigned short* __restrict__ Tb_us, const unsigned short* __restrict__ Rtb_us,
    unsigned short* __restrict__ Pb_us) {
    const __bf16* Tb = (const __bf16*)Tb_us;
    const __bf16* Rtb = (const __bf16*)Rtb_us;
    __bf16* Pb = (__bf16*)Pb_us;
    int blk = blockIdx.x;
    int b = blk >> 4, t = blk & 15;
    int tr = (t >> 2) * 64, tc = (t & 3) * 64;
    int tid = threadIdx.x, l = tid & 63, w = tid >> 6;
    int lr = l & 15, kofs = (l >> 4) * 8;
    const __bf16* Tbb = Tb + ((size_t)b << 16);
    f32x4 zero = {0.f, 0.f, 0.f, 0.f};
    f32x4 acc[4] = {zero, zero, zero, zero};
    int arow = tr + w * 16 + lr;
    for (int kk = 0; kk < 256; kk += 32) {
        bf16x8 af = *(const bf16x8*)&Tbb[(size_t)arow * 256 + kk + kofs];
#pragma unroll
        for (int j = 0; j < 4; ++j) {
            int brow = tc + j * 16 + lr;
            bf16x8 bb = *(const bf16x8*)&Rtb[(size_t)brow * 256 + kk + kofs];
            acc[j] = mfma16(af, bb, acc[j]);
        }
    }
    __bf16* Pbb = Pb + ((size_t)b << 16);
    int row0 = tr + w * 16 + ((l >> 4) << 2);
#pragma unroll
    for (int j = 0; j < 4; ++j) {
        int col = tc + j * 16 + lr;
#pragma unroll
        for (int r = 0; r < 4; ++r)
            Pbb[(size_t)(row0 + r) * 256 + col] = (__bf16)acc[j][r];
    }
}

// ---------------------------------------------------------------------------
// K3: out = P @ Qf + shift + Qf   (NT with Bt = Qft; fused BN + residual)
// grid (18 ntile, 2 ohalf, 8 b); 4 waves, each 64x64.
// ---------------------------------------------------------------------------
__global__ __launch_bounds__(256) void k_out(
    const unsigned short* __restrict__ Pb_us, const unsigned short* __restrict__ Qft_us,
    const float* __restrict__ Qf,
    const float* __restrict__ gamma, const float* __restrict__ beta,
    const float* __restrict__ mean, const float* __restrict__ var_,
    float* __restrict__ out) {
    const __bf16* Pb = (const __bf16*)Pb_us;
    const __bf16* Qft = (const __bf16*)Qft_us;
    int nt = blockIdx.x, oh = blockIdx.y, b = blockIdx.z;
    int tid = threadIdx.x, l = tid & 63, w = tid >> 6;
    int wr = w >> 1, wc = w & 1;
    int lr = l & 15, kofs = (l >> 4) * 8;
    int obase = oh * 128 + wr * 64;
    int nbase = nt * 128 + wc * 64;
    const __bf16* A = Pb + ((size_t)b << 16);
    const __bf16* Bt = Qft + (size_t)b * Nn * 256;
    f32x4 zero = {0.f, 0.f, 0.f, 0.f};
    f32x4 acc[4][4];
#pragma unroll
    for (int i = 0; i < 4; ++i)
#pragma unroll
        for (int j = 0; j < 4; ++j) acc[i][j] = zero;

    for (int kk = 0; kk < 256; kk += 32) {
        bf16x8 af[4], bb[4];
#pragma unroll
        for (int i = 0; i < 4; ++i)
            af[i] = *(const bf16x8*)&A[(size_t)(obase + i * 16 + lr) * 256 + kk + kofs];
#pragma unroll
        for (int j = 0; j < 4; ++j)
            bb[j] = *(const bf16x8*)&Bt[(size_t)(nbase + j * 16 + lr) * 256 + kk + kofs];
#pragma unroll
        for (int i = 0; i < 4; ++i)
#pragma unroll
            for (int j = 0; j < 4; ++j)
                acc[i][j] = mfma16(af[i], bb[j], acc[i][j]);
    }

    const float* Qfb = Qf + (size_t)b * Cc * Nn;
    float* outb = out + (size_t)b * Cc * Nn;
#pragma unroll
    for (int i = 0; i < 4; ++i) {
        int o0 = obase + i * 16 + ((l >> 4) << 2);
#pragma unroll
        for (int r = 0; r < 4; ++r) {
            int o = o0 + r;
            float inv = gamma[o] / sqrtf(var_[o] + EPS);
            float shift = beta[o] - mean[o] * inv;
#pragma unroll
            for (int j = 0; j < 4; ++j) {
                int n = nbase + j * 16 + lr;
                outb[(size_t)o * Nn + n] = acc[i][j][r] + shift + Qfb[(size_t)o * Nn + n];
            }
        }
    }
}

extern "C" void kernel_launch(void* const* d_in, const int* in_sizes, int n_in,
                              void* d_out, int out_size, void* d_ws, size_t ws_size,
                              hipStream_t stream) {
    (void)in_sizes; (void)n_in; (void)out_size; (void)ws_size;
    const float* Qf    = (const float*)d_in[0];
    const float* KVf   = (const float*)d_in[1];
    const float* Wq    = (const float*)d_in[2];
    const float* Wk    = (const float*)d_in[3];
    const float* Wv    = (const float*)d_in[4];
    const float* Wz    = (const float*)d_in[5];
    const float* gamma = (const float*)d_in[6];
    const float* beta  = (const float*)d_in[7];
    const float* mean  = (const float*)d_in[8];
    const float* var_  = (const float*)d_in[9];
    float* out = (float*)d_out;

    char* ws = (char*)d_ws;
    float* S            = (float*)ws;                                  // 8*256*256*4 = 2 MB
    unsigned short* Lb  = (unsigned short*)(ws + (2u << 20));          // 128 KB
    unsigned short* Rtb = (unsigned short*)(ws + (2u << 20) + (128u << 10));
    unsigned short* Tb  = (unsigned short*)(ws + (2u << 20) + (256u << 10));   // 1 MB
    unsigned short* Pb  = (unsigned short*)(ws + (3u << 20) + (256u << 10));   // 1 MB
    unsigned short* Qft = (unsigned short*)(ws + (4u << 20) + (256u << 10));   // 9.4 MB

    hipMemsetAsync(S, 0, (size_t)Bv * 256 * 256 * sizeof(float), stream);
    k_lr<<<512, 256, 0, stream>>>(Wq, Wk, Wv, Wz, gamma, var_, Lb, Rtb);
    k_transpose<<<dim3(4, 36, 8), 256, 0, stream>>>(Qf, Qft);
    k_syrk<<<256, 256, 0, stream>>>(KVf, S);
    k_LS<<<128, 256, 0, stream>>>(Lb, S, Tb);
    k_TR<<<128, 256, 0, stream>>>(Tb, Rtb, Pb);
    k_out<<<dim3(18, 2, 8), 256, 0, stream>>>(Pb, Qft, Qf, gamma, beta, mean, var_, out);
}